// Round 1
// 668.534 us; speedup vs baseline: 1.0616x; 1.0616x over previous
//
#include <hip/hip_runtime.h>
#include <hip/hip_bf16.h>
#include <stdint.h>

#define S 2048
#define D 2048
#define H 16
#define HD 128

typedef __bf16 bf16x8 __attribute__((ext_vector_type(8)));
typedef __bf16 bf16x4 __attribute__((ext_vector_type(4)));
typedef float f32x4 __attribute__((ext_vector_type(4)));

// async global->LDS DMA, 16B per lane; LDS dest = wave-uniform base + lane*16
__device__ __forceinline__ void gload16(const void* g, void* l) {
    __builtin_amdgcn_global_load_lds(
        (const __attribute__((address_space(1))) unsigned int*)g,
        (__attribute__((address_space(3))) unsigned int*)l, 16, 0, 0);
}

// ---------------- merged f32 -> bf16 convert (6 arrays, exact grid) ---------
struct CvtArgs { const float* src[6]; __bf16* dst[6]; };

__global__ void cvt_kn(CvtArgs a) {
    int which = blockIdx.x >> 12;                    // 4096 blocks per array
    int i = (blockIdx.x & 4095) * 256 + threadIdx.x; // < SD/4
    float4 v = reinterpret_cast<const float4*>(a.src[which])[i];
    bf16x4 o = { (__bf16)v.x, (__bf16)v.y, (__bf16)v.z, (__bf16)v.w };
    reinterpret_cast<bf16x4*>(a.dst[which])[i] = o;
}

// ---------------- fused multi-output GEMM -----------------------------------
// seg = blockIdx.x>>4 selects weight/bias/output/op.
// op: 0 = plain bf16, 1 = rope bf16 (q/k), 2 = direct-transpose bf16 (vT),
//     3 = plain f32
struct SegArgs {
    const __bf16* B[4];
    const float*  bias[4];
    void*         C[4];
    float         alpha[4];
    int           op[4];
};

__global__ __launch_bounds__(256) void gemm4_kn(const __bf16* __restrict__ A,
                                                SegArgs segs,
                                                const float* __restrict__ fcos,
                                                const float* __restrict__ fsin,
                                                int K) {
    __shared__ __bf16 As[128][32];   // unpadded: required by global_load_lds
    __shared__ __bf16 Bs[128][32];
    const int tid = threadIdx.x;
    const int wave = tid >> 6, lane = tid & 63;
    const int lr = lane & 15, lq = lane >> 4;
    const int wm = (wave >> 1) * 64, wn = (wave & 1) * 64;
    const int seg  = blockIdx.x >> 4;
    const int col0 = (blockIdx.x & 15) * 128;
    const int row0 = blockIdx.y * 128;
    const __bf16* __restrict__ Bp = segs.B[seg];

    f32x4 acc[4][4] = {};

    for (int k0 = 0; k0 < K; k0 += 32) {
#pragma unroll
        for (int i = 0; i < 2; i++) {
            int idx = tid + i * 256;             // 512 chunks of 8 bf16
            int r = idx >> 2, c = (idx & 3) * 8;
            gload16(&A [(size_t)(row0 + r) * K + k0 + c], &As[0][0] + idx * 8);
            gload16(&Bp[(size_t)(col0 + r) * K + k0 + c], &Bs[0][0] + idx * 8);
        }
        __syncthreads();
        bf16x8 af[4], bfr[4];
#pragma unroll
        for (int mt = 0; mt < 4; mt++)
            af[mt] = *reinterpret_cast<const bf16x8*>(&As[wm + mt * 16 + lr][lq * 8]);
#pragma unroll
        for (int nt = 0; nt < 4; nt++)
            bfr[nt] = *reinterpret_cast<const bf16x8*>(&Bs[wn + nt * 16 + lr][lq * 8]);
#pragma unroll
        for (int mt = 0; mt < 4; mt++)
#pragma unroll
            for (int nt = 0; nt < 4; nt++)
                acc[mt][nt] = __builtin_amdgcn_mfma_f32_16x16x32_bf16(af[mt], bfr[nt],
                                                                      acc[mt][nt], 0, 0, 0);
        __syncthreads();
    }
    const float* bias = segs.bias[seg];
    const float alpha = segs.alpha[seg];
    const int op = segs.op[seg];
    void* Cv = segs.C[seg];

    if (op == 2) {
        // direct transpose: vT[d][s], 4 consecutive rows per lane (8B store)
#pragma unroll
        for (int mt = 0; mt < 4; mt++)
#pragma unroll
            for (int nt = 0; nt < 4; nt++) {
                int col = col0 + wn + nt * 16 + lr;
                float bv = bias[col];
                int rowb = row0 + wm + mt * 16 + lq * 4;
                bf16x4 o4;
#pragma unroll
                for (int r = 0; r < 4; r++) o4[r] = (__bf16)(acc[mt][nt][r] + bv);
                *reinterpret_cast<bf16x4*>(&((__bf16*)Cv)[(size_t)col * S + rowb]) = o4;
            }
    } else if (op == 1) {
        // rope epilogue: pair partner value lives in lane lr^1
#pragma unroll
        for (int mt = 0; mt < 4; mt++)
#pragma unroll
            for (int nt = 0; nt < 4; nt++) {
                int col = col0 + wn + nt * 16 + lr;
                float bv = bias[col];
                int i = (col & 127) >> 1;
                int odd = lr & 1;
#pragma unroll
                for (int r = 0; r < 4; r++) {
                    int row = row0 + wm + mt * 16 + lq * 4 + r;
                    float v = alpha * (acc[mt][nt][r] + bv);
                    float p = __shfl_xor(v, 1, 64);
                    float c = fcos[row * 64 + i];
                    float sn = fsin[row * 64 + i];
                    float out = odd ? (p * sn + v * c) : (v * c - p * sn);
                    ((__bf16*)Cv)[(size_t)row * D + col] = (__bf16)out;
                }
            }
    } else {
#pragma unroll
        for (int mt = 0; mt < 4; mt++)
#pragma unroll
            for (int nt = 0; nt < 4; nt++) {
                int col = col0 + wn + nt * 16 + lr;
                float bv = bias[col];
#pragma unroll
                for (int r = 0; r < 4; r++) {
                    int row = row0 + wm + mt * 16 + lq * 4 + r;
                    float v = alpha * (acc[mt][nt][r] + bv);
                    if (op == 3)
                        ((float*)Cv)[(size_t)row * D + col] = v;
                    else
                        ((__bf16*)Cv)[(size_t)row * D + col] = (__bf16)v;
                }
            }
    }
}

// ---------------- fused attention (pipelined) -------------------------------
// Per t-tile: S = QK^T ; absacc += |S| ; {U += S@V, U2 += mask@V} merged.
// V + mask prefetched one full iteration ahead (V double-buffered in LDS,
// mask held in registers); K refilled after a raw mid-iteration s_barrier so
// its latency hides under the PV phase. The top __syncthreads' implicit
// vmcnt(0) drain only ever waits on data needed in the CURRENT iteration.
#define ATTN_STEP(T0, BUF, MC, MN)                                            \
  {                                                                           \
    __syncthreads(); /* drains vmcnt: K(i),V(i),mask(i) landed; waves sync */ \
    const int tnext = (T0) + 64;                                              \
    if (tnext < S) {                                                          \
      /* prefetch V(i+1) into the other buffer (covered by full iter) */      \
      _Pragma("unroll")                                                       \
      for (int i = 0; i < 4; i++) {                                           \
        int idx = tid + i * 256;                                              \
        int kc2 = idx >> 9, rv = (idx >> 2) & 127, cv = (idx & 3) * 8;        \
        gload16(&vT[(size_t)(h * HD + rv) * S + tnext + kc2 * 32 + cv],       \
                &Vs[(BUF) ^ 1][0][0][0] + idx * 8);                           \
      }                                                                       \
      /* prefetch mask(i+1) straight into registers (U2 A-fragment layout) */ \
      const float* mrow =                                                     \
          &mask[((size_t)h * S + qr0 + lr) * S + tnext + lq * 8];             \
      MN[0] = *reinterpret_cast<const float4*>(&mrow[0]);                     \
      MN[1] = *reinterpret_cast<const float4*>(&mrow[4]);                     \
      MN[2] = *reinterpret_cast<const float4*>(&mrow[32]);                    \
      MN[3] = *reinterpret_cast<const float4*>(&mrow[36]);                    \
    }                                                                         \
    /* ---- S phase: S = QK^T over current K tile ---- */                     \
    __builtin_amdgcn_s_setprio(1);                                            \
    _Pragma("unroll")                                                         \
    for (int ts = 0; ts < 4; ts++) {                                          \
      f32x4 c = {0.f, 0.f, 0.f, 0.f};                                         \
      _Pragma("unroll")                                                       \
      for (int kc = 0; kc < 4; kc++) {                                        \
        bf16x8 kf =                                                           \
            *reinterpret_cast<const bf16x8*>(&Ks[kc][ts * 16 + lr][lq * 8]);  \
        c = __builtin_amdgcn_mfma_f32_16x16x32_bf16(qf[kc], kf, c, 0, 0, 0);  \
      }                                                                       \
      _Pragma("unroll")                                                       \
      for (int r2 = 0; r2 < 4; r2++) {                                        \
        absacc[r2] += fabsf(c[r2]);                                           \
        Ps[wave][lq * 4 + r2][ts * 16 + lr] = (__bf16)c[r2];                  \
      }                                                                       \
    }                                                                         \
    __builtin_amdgcn_s_setprio(0);                                            \
    __builtin_amdgcn_s_barrier(); /* raw: all waves done reading Ks */        \
    if (tnext < S) {                                                          \
      /* refill K for next iter; latency covered by PV phase below */         \
      _Pragma("unroll")                                                       \
      for (int i = 0; i < 4; i++) {                                           \
        int idx = tid + i * 256;                                              \
        int rk = (idx >> 2) & 63, ck = (idx & 3) * 8;                         \
        gload16(&k[(size_t)(tnext + rk) * D + h * HD + i * 32 + ck],          \
                &Ks[0][0][0] + idx * 8);                                      \
      }                                                                       \
    }                                                                         \
    /* ---- PV phase: each vf feeds BOTH U2 (mask regs) and U (Ps) ---- */    \
    __builtin_amdgcn_s_setprio(1);                                            \
    _Pragma("unroll")                                                         \
    for (int kc2 = 0; kc2 < 2; kc2++) {                                       \
      bf16x8 pfm;                                                             \
      pfm[0] = (__bf16)MC[kc2 * 2].x;     pfm[1] = (__bf16)MC[kc2 * 2].y;     \
      pfm[2] = (__bf16)MC[kc2 * 2].z;     pfm[3] = (__bf16)MC[kc2 * 2].w;     \
      pfm[4] = (__bf16)MC[kc2 * 2 + 1].x; pfm[5] = (__bf16)MC[kc2 * 2 + 1].y; \
      pfm[6] = (__bf16)MC[kc2 * 2 + 1].z; pfm[7] = (__bf16)MC[kc2 * 2 + 1].w; \
      bf16x8 pfs =                                                            \
          *reinterpret_cast<const bf16x8*>(&Ps[wave][lr][kc2 * 32 + lq * 8]); \
      _Pragma("unroll")                                                       \
      for (int nt = 0; nt < 8; nt++) {                                        \
        bf16x8 vf = *reinterpret_cast<const bf16x8*>(                         \
            &Vs[BUF][kc2][nt * 16 + lr][lq * 8]);                             \
        U2[nt] = __builtin_amdgcn_mfma_f32_16x16x32_bf16(pfm, vf, U2[nt], 0, 0, 0); \
        U[nt]  = __builtin_amdgcn_mfma_f32_16x16x32_bf16(pfs, vf, U[nt], 0, 0, 0);  \
      }                                                                       \
    }                                                                         \
    __builtin_amdgcn_s_setprio(0);                                            \
  }

__global__ __launch_bounds__(256) void attn_kn(const __bf16* __restrict__ q,
                                               const __bf16* __restrict__ k,
                                               const __bf16* __restrict__ vT,
                                               const float* __restrict__ mask,
                                               const __bf16* __restrict__ g,
                                               const float* __restrict__ norm_w,
                                               __bf16* __restrict__ attn) {
    __shared__ __bf16 Ks[4][64][32];       // K tile (single-buffered)
    __shared__ __bf16 Vs[2][2][128][32];   // V tile, double-buffered
    __shared__ __bf16 Ps[4][16][72];       // per-wave P tile (16 q-rows x 64 t)

    // XCD-grouping swizzle: 512 blocks, 64 per XCD -> each XCD covers 2 heads
    const int bid = blockIdx.x + (blockIdx.y << 5);
    const int slot = bid >> 3;
    const int h = ((bid & 7) << 1) | (slot >> 5);
    const int qt = slot & 31;

    const int tid = threadIdx.x, wave = tid >> 6, lane = tid & 63;
    const int lr = lane & 15, lq = lane >> 4;
    const int qr0 = qt * 64 + wave * 16;

    bf16x8 qf[4];
#pragma unroll
    for (int kc = 0; kc < 4; kc++)
        qf[kc] = *reinterpret_cast<const bf16x8*>(
            &q[(size_t)(qr0 + lr) * D + h * HD + kc * 32 + lq * 8]);

    float absacc[4] = {0.f, 0.f, 0.f, 0.f};
    f32x4 U[8] = {};
    f32x4 U2[8] = {};
    float4 m_a[4], m_b[4];

    // ---- prologue: stage K(0), V(0)->Vs[0], mask(0)->m_a ----
#pragma unroll
    for (int i = 0; i < 4; i++) {
        int idx = tid + i * 256;
        int rk = (idx >> 2) & 63, ck = (idx & 3) * 8;
        gload16(&k[(size_t)rk * D + h * HD + i * 32 + ck], &Ks[0][0][0] + idx * 8);
    }
#pragma unroll
    for (int i = 0; i < 4; i++) {
        int idx = tid + i * 256;
        int kc2 = idx >> 9, rv = (idx >> 2) & 127, cv = (idx & 3) * 8;
        gload16(&vT[(size_t)(h * HD + rv) * S + kc2 * 32 + cv],
                &Vs[0][0][0][0] + idx * 8);
    }
    {
        const float* mrow = &mask[((size_t)h * S + qr0 + lr) * S + lq * 8];
        m_a[0] = *reinterpret_cast<const float4*>(&mrow[0]);
        m_a[1] = *reinterpret_cast<const float4*>(&mrow[4]);
        m_a[2] = *reinterpret_cast<const float4*>(&mrow[32]);
        m_a[3] = *reinterpret_cast<const float4*>(&mrow[36]);
    }

    for (int t0 = 0; t0 < S; t0 += 128) {
        ATTN_STEP(t0,      0, m_a, m_b)
        ATTN_STEP(t0 + 64, 1, m_b, m_a)
    }

    // rd = 1/clip(sum_t |S|)
    float rd[4];
#pragma unroll
    for (int r2 = 0; r2 < 4; r2++) {
        float v = absacc[r2];
#pragma unroll
        for (int off = 1; off < 16; off <<= 1) v += __shfl_xor(v, off, 64);
        rd[r2] = 1.0f / fminf(fmaxf(v, 1.0f), 50000.0f);
    }

    // O = rd*U + U2, RMS over hd, * norm_w * g
    float otot[8][4];
    float ssum[4] = {0.f, 0.f, 0.f, 0.f};
#pragma unroll
    for (int nt = 0; nt < 8; nt++)
#pragma unroll
        for (int r2 = 0; r2 < 4; r2++) {
            float v = U[nt][r2] * rd[r2] + U2[nt][r2];
            otot[nt][r2] = v;
            ssum[r2] += v * v;
        }
#pragma unroll
    for (int r2 = 0; r2 < 4; r2++) {
#pragma unroll
        for (int off = 1; off < 16; off <<= 1) ssum[r2] += __shfl_xor(ssum[r2], off, 64);
    }
    float rinv[4];
#pragma unroll
    for (int r2 = 0; r2 < 4; r2++) rinv[r2] = rsqrtf(ssum[r2] * (1.0f / HD) + 1e-5f);
#pragma unroll
    for (int nt = 0; nt < 8; nt++) {
        int col = nt * 16 + lr;
        float nw = norm_w[col];
#pragma unroll
        for (int r2 = 0; r2 < 4; r2++) {
            int row = qr0 + lq * 4 + r2;
            float val = otot[nt][r2] * rinv[r2] * nw * (float)g[(size_t)row * D + h * HD + col];
            attn[(size_t)row * D + h * HD + col] = (__bf16)val;
        }
    }
}

extern "C" void kernel_launch(void* const* d_in, const int* in_sizes, int n_in,
                              void* d_out, int out_size, void* d_ws, size_t ws_size,
                              hipStream_t stream) {
    const float* x    = (const float*)d_in[0];
    const float* fcos = (const float*)d_in[1];
    const float* fsin = (const float*)d_in[2];
    const float* mask = (const float*)d_in[3];
    const float* Wq   = (const float*)d_in[4];
    const float* bq   = (const float*)d_in[5];
    const float* Wk   = (const float*)d_in[6];
    const float* bk   = (const float*)d_in[7];
    const float* Wv   = (const float*)d_in[8];
    const float* bv   = (const float*)d_in[9];
    const float* Wg   = (const float*)d_in[10];
    const float* bg   = (const float*)d_in[11];
    const float* Wp   = (const float*)d_in[12];
    const float* bp   = (const float*)d_in[13];
    const float* normw= (const float*)d_in[14];

    char* w = (char*)d_ws;
    auto alloc = [&](size_t b) { void* p = (void*)w; w += (b + 255) & ~(size_t)255; return p; };
    const size_t SD = (size_t)S * D;

    __bf16* xb  = (__bf16*)alloc(SD * 2);
    __bf16* wqb = (__bf16*)alloc(SD * 2);
    __bf16* wkb = (__bf16*)alloc(SD * 2);
    __bf16* wvb = (__bf16*)alloc(SD * 2);
    __bf16* wgb = (__bf16*)alloc(SD * 2);
    __bf16* wpb = (__bf16*)alloc(SD * 2);
    __bf16* qb  = (__bf16*)alloc(SD * 2);
    __bf16* kb  = (__bf16*)alloc(SD * 2);
    __bf16* vTb = (__bf16*)alloc(SD * 2);
    __bf16* gb  = (__bf16*)alloc(SD * 2);
    __bf16* atb = xb;   // alias: xb dead after QKVG gemm

    CvtArgs ca;
    ca.src[0] = x;  ca.dst[0] = xb;
    ca.src[1] = Wq; ca.dst[1] = wqb;
    ca.src[2] = Wk; ca.dst[2] = wkb;
    ca.src[3] = Wv; ca.dst[3] = wvb;
    ca.src[4] = Wg; ca.dst[4] = wgb;
    ca.src[5] = Wp; ca.dst[5] = wpb;
    cvt_kn<<<6 * 4096, 256, 0, stream>>>(ca);

    const float scaling = 0.08838834764831845f;  // 128^-0.5
    SegArgs qkvg;
    qkvg.B[0] = wqb; qkvg.B[1] = wkb; qkvg.B[2] = wvb; qkvg.B[3] = wgb;
    qkvg.bias[0] = bq; qkvg.bias[1] = bk; qkvg.bias[2] = bv; qkvg.bias[3] = bg;
    qkvg.C[0] = qb; qkvg.C[1] = kb; qkvg.C[2] = vTb; qkvg.C[3] = gb;
    qkvg.alpha[0] = 1.0f; qkvg.alpha[1] = scaling; qkvg.alpha[2] = 1.0f; qkvg.alpha[3] = 1.0f;
    qkvg.op[0] = 1; qkvg.op[1] = 1; qkvg.op[2] = 2; qkvg.op[3] = 0;
    gemm4_kn<<<dim3(64, 16), 256, 0, stream>>>(xb, qkvg, fcos, fsin, D);

    attn_kn<<<dim3(32, 16), 256, 0, stream>>>(qb, kb, vTb, mask, gb, normw, atb);

    SegArgs pseg;
    pseg.B[0] = pseg.B[1] = pseg.B[2] = pseg.B[3] = wpb;
    pseg.bias[0] = pseg.bias[1] = pseg.bias[2] = pseg.bias[3] = bp;
    pseg.C[0] = pseg.C[1] = pseg.C[2] = pseg.C[3] = d_out;
    pseg.alpha[0] = pseg.alpha[1] = pseg.alpha[2] = pseg.alpha[3] = 1.0f;
    pseg.op[0] = pseg.op[1] = pseg.op[2] = pseg.op[3] = 3;
    gemm4_kn<<<dim3(16, 16), 256, 0, stream>>>(atb, pseg, fcos, fsin, D);
}

// Round 2
// 653.865 us; speedup vs baseline: 1.0855x; 1.0224x over previous
//
#include <hip/hip_runtime.h>
#include <hip/hip_bf16.h>
#include <stdint.h>

#define S 2048
#define D 2048
#define H 16
#define HD 128

typedef __bf16 bf16x8 __attribute__((ext_vector_type(8)));
typedef __bf16 bf16x4 __attribute__((ext_vector_type(4)));
typedef float f32x4 __attribute__((ext_vector_type(4)));

// async global->LDS DMA, 16B per lane; LDS dest = wave-uniform base + lane*16
__device__ __forceinline__ void gload16(const void* g, void* l) {
    __builtin_amdgcn_global_load_lds(
        (const __attribute__((address_space(1))) unsigned int*)g,
        (__attribute__((address_space(3))) unsigned int*)l, 16, 0, 0);
}

// ---------------- merged f32 -> bf16 convert (6 arrays, exact grid) ---------
struct CvtArgs { const float* src[6]; __bf16* dst[6]; };

__global__ void cvt_kn(CvtArgs a) {
    int which = blockIdx.x >> 12;                    // 4096 blocks per array
    int i = (blockIdx.x & 4095) * 256 + threadIdx.x; // < SD/4
    float4 v = reinterpret_cast<const float4*>(a.src[which])[i];
    bf16x4 o = { (__bf16)v.x, (__bf16)v.y, (__bf16)v.z, (__bf16)v.w };
    reinterpret_cast<bf16x4*>(a.dst[which])[i] = o;
}

// ---------------- fused multi-output GEMM (2-phase prefetch) ----------------
// seg = blockIdx.x>>4 selects weight/bias/output/op.
// op: 0 = plain bf16, 1 = rope bf16 (q/k), 2 = direct-transpose bf16 (vT),
//     3 = plain f32
// K-loop is the catalog's "minimum 2-phase": double-buffered LDS, ONE
// __syncthreads per K-step (drains exactly the current tile's loads), and
// next-tile global_load_lds issued right after the barrier so HBM latency
// hides under the 16-MFMA compute phase.
struct SegArgs {
    const __bf16* B[4];
    const float*  bias[4];
    void*         C[4];
    float         alpha[4];
    int           op[4];
};

__global__ __launch_bounds__(256) void gemm4_kn(const __bf16* __restrict__ A,
                                                SegArgs segs,
                                                const float* __restrict__ fcos,
                                                const float* __restrict__ fsin,
                                                int K) {
    __shared__ __bf16 As[2][128][32];   // unpadded: required by global_load_lds
    __shared__ __bf16 Bs[2][128][32];
    const int tid = threadIdx.x;
    const int wave = tid >> 6, lane = tid & 63;
    const int lr = lane & 15, lq = lane >> 4;
    const int wm = (wave >> 1) * 64, wn = (wave & 1) * 64;
    const int seg  = blockIdx.x >> 4;
    const int col0 = (blockIdx.x & 15) * 128;
    const int row0 = blockIdx.y * 128;
    const __bf16* __restrict__ Bp = segs.B[seg];

    // per-thread staging coords (512 chunks of 8 bf16 per 128x32 tile)
    const int sr0 = tid >> 2, sc = (tid & 3) * 8;   // i=0 row; i=1 row = sr0+64

    f32x4 acc[4][4] = {};

    // prologue: stage K-tile 0 into buffer 0
#pragma unroll
    for (int i = 0; i < 2; i++) {
        int r = sr0 + i * 64, idx = tid + i * 256;
        gload16(&A [(size_t)(row0 + r) * K + sc], &As[0][0][0] + idx * 8);
        gload16(&Bp[(size_t)(col0 + r) * K + sc], &Bs[0][0][0] + idx * 8);
    }

    int buf = 0;
    for (int k0 = 0; k0 < K; k0 += 32) {
        __syncthreads();    // implicit vmcnt(0): tile k0 resident in As/Bs[buf]
        if (k0 + 32 < K) {  // issue next tile into other buffer; lands at next barrier
#pragma unroll
            for (int i = 0; i < 2; i++) {
                int r = sr0 + i * 64, idx = tid + i * 256;
                gload16(&A [(size_t)(row0 + r) * K + k0 + 32 + sc],
                        &As[buf ^ 1][0][0] + idx * 8);
                gload16(&Bp[(size_t)(col0 + r) * K + k0 + 32 + sc],
                        &Bs[buf ^ 1][0][0] + idx * 8);
            }
        }
        bf16x8 af[4], bfr[4];
#pragma unroll
        for (int mt = 0; mt < 4; mt++)
            af[mt] = *reinterpret_cast<const bf16x8*>(&As[buf][wm + mt * 16 + lr][lq * 8]);
#pragma unroll
        for (int nt = 0; nt < 4; nt++)
            bfr[nt] = *reinterpret_cast<const bf16x8*>(&Bs[buf][wn + nt * 16 + lr][lq * 8]);
        __builtin_amdgcn_s_setprio(1);
#pragma unroll
        for (int mt = 0; mt < 4; mt++)
#pragma unroll
            for (int nt = 0; nt < 4; nt++)
                acc[mt][nt] = __builtin_amdgcn_mfma_f32_16x16x32_bf16(af[mt], bfr[nt],
                                                                      acc[mt][nt], 0, 0, 0);
        __builtin_amdgcn_s_setprio(0);
        buf ^= 1;
    }
    const float* bias = segs.bias[seg];
    const float alpha = segs.alpha[seg];
    const int op = segs.op[seg];
    void* Cv = segs.C[seg];

    if (op == 2) {
        // direct transpose: vT[d][s], 4 consecutive rows per lane (8B store)
#pragma unroll
        for (int mt = 0; mt < 4; mt++)
#pragma unroll
            for (int nt = 0; nt < 4; nt++) {
                int col = col0 + wn + nt * 16 + lr;
                float bv = bias[col];
                int rowb = row0 + wm + mt * 16 + lq * 4;
                bf16x4 o4;
#pragma unroll
                for (int r = 0; r < 4; r++) o4[r] = (__bf16)(acc[mt][nt][r] + bv);
                *reinterpret_cast<bf16x4*>(&((__bf16*)Cv)[(size_t)col * S + rowb]) = o4;
            }
    } else if (op == 1) {
        // rope epilogue: pair partner value lives in lane lr^1
#pragma unroll
        for (int mt = 0; mt < 4; mt++)
#pragma unroll
            for (int nt = 0; nt < 4; nt++) {
                int col = col0 + wn + nt * 16 + lr;
                float bv = bias[col];
                int i = (col & 127) >> 1;
                int odd = lr & 1;
#pragma unroll
                for (int r = 0; r < 4; r++) {
                    int row = row0 + wm + mt * 16 + lq * 4 + r;
                    float v = alpha * (acc[mt][nt][r] + bv);
                    float p = __shfl_xor(v, 1, 64);
                    float c = fcos[row * 64 + i];
                    float sn = fsin[row * 64 + i];
                    float out = odd ? (p * sn + v * c) : (v * c - p * sn);
                    ((__bf16*)Cv)[(size_t)row * D + col] = (__bf16)out;
                }
            }
    } else {
#pragma unroll
        for (int mt = 0; mt < 4; mt++)
#pragma unroll
            for (int nt = 0; nt < 4; nt++) {
                int col = col0 + wn + nt * 16 + lr;
                float bv = bias[col];
#pragma unroll
                for (int r = 0; r < 4; r++) {
                    int row = row0 + wm + mt * 16 + lq * 4 + r;
                    float v = alpha * (acc[mt][nt][r] + bv);
                    if (op == 3)
                        ((float*)Cv)[(size_t)row * D + col] = v;
                    else
                        ((__bf16*)Cv)[(size_t)row * D + col] = (__bf16)v;
                }
            }
    }
}

// ---------------- fused attention (pipelined) -------------------------------
// Per t-tile: S = QK^T ; absacc += |S| ; {U += S@V, U2 += mask@V} merged.
// V + mask prefetched one full iteration ahead (V double-buffered in LDS,
// mask held in registers); K refilled after a raw mid-iteration s_barrier so
// its latency hides under the PV phase. The top __syncthreads' implicit
// vmcnt(0) drain only ever waits on data needed in the CURRENT iteration.
#define ATTN_STEP(T0, BUF, MC, MN)                                            \
  {                                                                           \
    __syncthreads(); /* drains vmcnt: K(i),V(i),mask(i) landed; waves sync */ \
    const int tnext = (T0) + 64;                                              \
    if (tnext < S) {                                                          \
      /* prefetch V(i+1) into the other buffer (covered by full iter) */      \
      _Pragma("unroll")                                                       \
      for (int i = 0; i < 4; i++) {                                           \
        int idx = tid + i * 256;                                              \
        int kc2 = idx >> 9, rv = (idx >> 2) & 127, cv = (idx & 3) * 8;        \
        gload16(&vT[(size_t)(h * HD + rv) * S + tnext + kc2 * 32 + cv],       \
                &Vs[(BUF) ^ 1][0][0][0] + idx * 8);                           \
      }                                                                       \
      /* prefetch mask(i+1) straight into registers (U2 A-fragment layout) */ \
      const float* mrow =                                                     \
          &mask[((size_t)h * S + qr0 + lr) * S + tnext + lq * 8];             \
      MN[0] = *reinterpret_cast<const float4*>(&mrow[0]);                     \
      MN[1] = *reinterpret_cast<const float4*>(&mrow[4]);                     \
      MN[2] = *reinterpret_cast<const float4*>(&mrow[32]);                    \
      MN[3] = *reinterpret_cast<const float4*>(&mrow[36]);                    \
    }                                                                         \
    /* ---- S phase: S = QK^T over current K tile ---- */                     \
    __builtin_amdgcn_s_setprio(1);                                            \
    _Pragma("unroll")                                                         \
    for (int ts = 0; ts < 4; ts++) {                                          \
      f32x4 c = {0.f, 0.f, 0.f, 0.f};                                         \
      _Pragma("unroll")                                                       \
      for (int kc = 0; kc < 4; kc++) {                                        \
        bf16x8 kf =                                                           \
            *reinterpret_cast<const bf16x8*>(&Ks[kc][ts * 16 + lr][lq * 8]);  \
        c = __builtin_amdgcn_mfma_f32_16x16x32_bf16(qf[kc], kf, c, 0, 0, 0);  \
      }                                                                       \
      _Pragma("unroll")                                                       \
      for (int r2 = 0; r2 < 4; r2++) {                                        \
        absacc[r2] += fabsf(c[r2]);                                           \
        Ps[wave][lq * 4 + r2][ts * 16 + lr] = (__bf16)c[r2];                  \
      }                                                                       \
    }                                                                         \
    __builtin_amdgcn_s_setprio(0);                                            \
    __builtin_amdgcn_s_barrier(); /* raw: all waves done reading Ks */        \
    if (tnext < S) {                                                          \
      /* refill K for next iter; latency covered by PV phase below */         \
      _Pragma("unroll")                                                       \
      for (int i = 0; i < 4; i++) {                                           \
        int idx = tid + i * 256;                                              \
        int rk = (idx >> 2) & 63, ck = (idx & 3) * 8;                         \
        gload16(&k[(size_t)(tnext + rk) * D + h * HD + i * 32 + ck],          \
                &Ks[0][0][0] + idx * 8);                                      \
      }                                                                       \
    }                                                                         \
    /* ---- PV phase: each vf feeds BOTH U2 (mask regs) and U (Ps) ---- */    \
    __builtin_amdgcn_s_setprio(1);                                            \
    _Pragma("unroll")                                                         \
    for (int kc2 = 0; kc2 < 2; kc2++) {                                       \
      bf16x8 pfm;                                                             \
      pfm[0] = (__bf16)MC[kc2 * 2].x;     pfm[1] = (__bf16)MC[kc2 * 2].y;     \
      pfm[2] = (__bf16)MC[kc2 * 2].z;     pfm[3] = (__bf16)MC[kc2 * 2].w;     \
      pfm[4] = (__bf16)MC[kc2 * 2 + 1].x; pfm[5] = (__bf16)MC[kc2 * 2 + 1].y; \
      pfm[6] = (__bf16)MC[kc2 * 2 + 1].z; pfm[7] = (__bf16)MC[kc2 * 2 + 1].w; \
      bf16x8 pfs =                                                            \
          *reinterpret_cast<const bf16x8*>(&Ps[wave][lr][kc2 * 32 + lq * 8]); \
      _Pragma("unroll")                                                       \
      for (int nt = 0; nt < 8; nt++) {                                        \
        bf16x8 vf = *reinterpret_cast<const bf16x8*>(                         \
            &Vs[BUF][kc2][nt * 16 + lr][lq * 8]);                             \
        U2[nt] = __builtin_amdgcn_mfma_f32_16x16x32_bf16(pfm, vf, U2[nt], 0, 0, 0); \
        U[nt]  = __builtin_amdgcn_mfma_f32_16x16x32_bf16(pfs, vf, U[nt], 0, 0, 0);  \
      }                                                                       \
    }                                                                         \
    __builtin_amdgcn_s_setprio(0);                                            \
  }

__global__ __launch_bounds__(256) void attn_kn(const __bf16* __restrict__ q,
                                               const __bf16* __restrict__ k,
                                               const __bf16* __restrict__ vT,
                                               const float* __restrict__ mask,
                                               const __bf16* __restrict__ g,
                                               const float* __restrict__ norm_w,
                                               __bf16* __restrict__ attn) {
    __shared__ __bf16 Ks[4][64][32];       // K tile (single-buffered)
    __shared__ __bf16 Vs[2][2][128][32];   // V tile, double-buffered
    __shared__ __bf16 Ps[4][16][72];       // per-wave P tile (16 q-rows x 64 t)

    // XCD-grouping swizzle: 512 blocks, 64 per XCD -> each XCD covers 2 heads
    const int bid = blockIdx.x + (blockIdx.y << 5);
    const int slot = bid >> 3;
    const int h = ((bid & 7) << 1) | (slot >> 5);
    const int qt = slot & 31;

    const int tid = threadIdx.x, wave = tid >> 6, lane = tid & 63;
    const int lr = lane & 15, lq = lane >> 4;
    const int qr0 = qt * 64 + wave * 16;

    bf16x8 qf[4];
#pragma unroll
    for (int kc = 0; kc < 4; kc++)
        qf[kc] = *reinterpret_cast<const bf16x8*>(
            &q[(size_t)(qr0 + lr) * D + h * HD + kc * 32 + lq * 8]);

    float absacc[4] = {0.f, 0.f, 0.f, 0.f};
    f32x4 U[8] = {};
    f32x4 U2[8] = {};
    float4 m_a[4], m_b[4];

    // ---- prologue: stage K(0), V(0)->Vs[0], mask(0)->m_a ----
#pragma unroll
    for (int i = 0; i < 4; i++) {
        int idx = tid + i * 256;
        int rk = (idx >> 2) & 63, ck = (idx & 3) * 8;
        gload16(&k[(size_t)rk * D + h * HD + i * 32 + ck], &Ks[0][0][0] + idx * 8);
    }
#pragma unroll
    for (int i = 0; i < 4; i++) {
        int idx = tid + i * 256;
        int kc2 = idx >> 9, rv = (idx >> 2) & 127, cv = (idx & 3) * 8;
        gload16(&vT[(size_t)(h * HD + rv) * S + kc2 * 32 + cv],
                &Vs[0][0][0][0] + idx * 8);
    }
    {
        const float* mrow = &mask[((size_t)h * S + qr0 + lr) * S + lq * 8];
        m_a[0] = *reinterpret_cast<const float4*>(&mrow[0]);
        m_a[1] = *reinterpret_cast<const float4*>(&mrow[4]);
        m_a[2] = *reinterpret_cast<const float4*>(&mrow[32]);
        m_a[3] = *reinterpret_cast<const float4*>(&mrow[36]);
    }

    for (int t0 = 0; t0 < S; t0 += 128) {
        ATTN_STEP(t0,      0, m_a, m_b)
        ATTN_STEP(t0 + 64, 1, m_b, m_a)
    }

    // rd = 1/clip(sum_t |S|)
    float rd[4];
#pragma unroll
    for (int r2 = 0; r2 < 4; r2++) {
        float v = absacc[r2];
#pragma unroll
        for (int off = 1; off < 16; off <<= 1) v += __shfl_xor(v, off, 64);
        rd[r2] = 1.0f / fminf(fmaxf(v, 1.0f), 50000.0f);
    }

    // O = rd*U + U2, RMS over hd, * norm_w * g
    float otot[8][4];
    float ssum[4] = {0.f, 0.f, 0.f, 0.f};
#pragma unroll
    for (int nt = 0; nt < 8; nt++)
#pragma unroll
        for (int r2 = 0; r2 < 4; r2++) {
            float v = U[nt][r2] * rd[r2] + U2[nt][r2];
            otot[nt][r2] = v;
            ssum[r2] += v * v;
        }
#pragma unroll
    for (int r2 = 0; r2 < 4; r2++) {
#pragma unroll
        for (int off = 1; off < 16; off <<= 1) ssum[r2] += __shfl_xor(ssum[r2], off, 64);
    }
    float rinv[4];
#pragma unroll
    for (int r2 = 0; r2 < 4; r2++) rinv[r2] = rsqrtf(ssum[r2] * (1.0f / HD) + 1e-5f);
#pragma unroll
    for (int nt = 0; nt < 8; nt++) {
        int col = nt * 16 + lr;
        float nw = norm_w[col];
#pragma unroll
        for (int r2 = 0; r2 < 4; r2++) {
            int row = qr0 + lq * 4 + r2;
            float val = otot[nt][r2] * rinv[r2] * nw * (float)g[(size_t)row * D + h * HD + col];
            attn[(size_t)row * D + h * HD + col] = (__bf16)val;
        }
    }
}

extern "C" void kernel_launch(void* const* d_in, const int* in_sizes, int n_in,
                              void* d_out, int out_size, void* d_ws, size_t ws_size,
                              hipStream_t stream) {
    const float* x    = (const float*)d_in[0];
    const float* fcos = (const float*)d_in[1];
    const float* fsin = (const float*)d_in[2];
    const float* mask = (const float*)d_in[3];
    const float* Wq   = (const float*)d_in[4];
    const float* bq   = (const float*)d_in[5];
    const float* Wk   = (const float*)d_in[6];
    const float* bk   = (const float*)d_in[7];
    const float* Wv   = (const float*)d_in[8];
    const float* bv   = (const float*)d_in[9];
    const float* Wg   = (const float*)d_in[10];
    const float* bg   = (const float*)d_in[11];
    const float* Wp   = (const float*)d_in[12];
    const float* bp   = (const float*)d_in[13];
    const float* normw= (const float*)d_in[14];

    char* w = (char*)d_ws;
    auto alloc = [&](size_t b) { void* p = (void*)w; w += (b + 255) & ~(size_t)255; return p; };
    const size_t SD = (size_t)S * D;

    __bf16* xb  = (__bf16*)alloc(SD * 2);
    __bf16* wqb = (__bf16*)alloc(SD * 2);
    __bf16* wkb = (__bf16*)alloc(SD * 2);
    __bf16* wvb = (__bf16*)alloc(SD * 2);
    __bf16* wgb = (__bf16*)alloc(SD * 2);
    __bf16* wpb = (__bf16*)alloc(SD * 2);
    __bf16* qb  = (__bf16*)alloc(SD * 2);
    __bf16* kb  = (__bf16*)alloc(SD * 2);
    __bf16* vTb = (__bf16*)alloc(SD * 2);
    __bf16* gb  = (__bf16*)alloc(SD * 2);
    __bf16* atb = xb;   // alias: xb dead after QKVG gemm

    CvtArgs ca;
    ca.src[0] = x;  ca.dst[0] = xb;
    ca.src[1] = Wq; ca.dst[1] = wqb;
    ca.src[2] = Wk; ca.dst[2] = wkb;
    ca.src[3] = Wv; ca.dst[3] = wvb;
    ca.src[4] = Wg; ca.dst[4] = wgb;
    ca.src[5] = Wp; ca.dst[5] = wpb;
    cvt_kn<<<6 * 4096, 256, 0, stream>>>(ca);

    const float scaling = 0.08838834764831845f;  // 128^-0.5
    SegArgs qkvg;
    qkvg.B[0] = wqb; qkvg.B[1] = wkb; qkvg.B[2] = wvb; qkvg.B[3] = wgb;
    qkvg.bias[0] = bq; qkvg.bias[1] = bk; qkvg.bias[2] = bv; qkvg.bias[3] = bg;
    qkvg.C[0] = qb; qkvg.C[1] = kb; qkvg.C[2] = vTb; qkvg.C[3] = gb;
    qkvg.alpha[0] = 1.0f; qkvg.alpha[1] = scaling; qkvg.alpha[2] = 1.0f; qkvg.alpha[3] = 1.0f;
    qkvg.op[0] = 1; qkvg.op[1] = 1; qkvg.op[2] = 2; qkvg.op[3] = 0;
    gemm4_kn<<<dim3(64, 16), 256, 0, stream>>>(xb, qkvg, fcos, fsin, D);

    attn_kn<<<dim3(32, 16), 256, 0, stream>>>(qb, kb, vTb, mask, gb, normw, atb);

    SegArgs pseg;
    pseg.B[0] = pseg.B[1] = pseg.B[2] = pseg.B[3] = wpb;
    pseg.bias[0] = pseg.bias[1] = pseg.bias[2] = pseg.bias[3] = bp;
    pseg.C[0] = pseg.C[1] = pseg.C[2] = pseg.C[3] = d_out;
    pseg.alpha[0] = pseg.alpha[1] = pseg.alpha[2] = pseg.alpha[3] = 1.0f;
    pseg.op[0] = pseg.op[1] = pseg.op[2] = pseg.op[3] = 3;
    gemm4_kn<<<dim3(16, 16), 256, 0, stream>>>(atb, pseg, fcos, fsin, D);
}

// Round 4
// 637.111 us; speedup vs baseline: 1.1140x; 1.0263x over previous
//
#include <hip/hip_runtime.h>
#include <hip/hip_bf16.h>
#include <stdint.h>

#define S 2048
#define D 2048
#define H 16
#define HD 128

typedef __bf16 bf16x8 __attribute__((ext_vector_type(8)));
typedef __bf16 bf16x4 __attribute__((ext_vector_type(4)));
typedef float f32x4 __attribute__((ext_vector_type(4)));

// async global->LDS DMA, 16B per lane; LDS dest = wave-uniform base + lane*16
__device__ __forceinline__ void gload16(const void* g, void* l) {
    __builtin_amdgcn_global_load_lds(
        (const __attribute__((address_space(1))) unsigned int*)g,
        (__attribute__((address_space(3))) unsigned int*)l, 16, 0, 0);
}

// ---------------- merged f32 -> bf16 convert (6 arrays, exact grid) ---------
struct CvtArgs { const float* src[6]; __bf16* dst[6]; };

__global__ void cvt_kn(CvtArgs a) {
    int which = blockIdx.x >> 12;                    // 4096 blocks per array
    int i = (blockIdx.x & 4095) * 256 + threadIdx.x; // < SD/4
    float4 v = reinterpret_cast<const float4*>(a.src[which])[i];
    bf16x4 o = { (__bf16)v.x, (__bf16)v.y, (__bf16)v.z, (__bf16)v.w };
    reinterpret_cast<bf16x4*>(a.dst[which])[i] = o;
}

// ---------------- QKVG GEMM: 256x256 tile, 2-phase prefetch -----------------
// 512 threads = 8 waves (2 M-waves x 4 N-waves), per-wave 128x64 output.
// Compute phase per barrier interval = 32 MFMA/wave (~1200 cyc/CU interval)
// >> global->LDS latency, so the prefetch issued right after the barrier is
// fully covered (this was NOT true at 128^2: only 16 MFMA/wave).
// op: 0 = plain bf16, 1 = rope bf16 (q/k), 2 = direct-transpose bf16 (vT)
struct SegArgs {
    const __bf16* B[4];
    const float*  bias[4];
    void*         C[4];
    float         alpha[4];
    int           op[4];
};

__global__ __launch_bounds__(512) void gemm256_kn(const __bf16* __restrict__ A,
                                                  SegArgs segs,
                                                  const float* __restrict__ fcos,
                                                  const float* __restrict__ fsin,
                                                  int K) {
    __shared__ __bf16 As[2][256][32];   // 32 KB  (unpadded: global_load_lds)
    __shared__ __bf16 Bs[2][256][32];   // 32 KB
    const int tid = threadIdx.x;
    const int wave = tid >> 6, lane = tid & 63;
    const int lr = lane & 15, lq = lane >> 4;
    const int wm = (wave >> 2) * 128, wn = (wave & 3) * 64;
    const int seg  = blockIdx.x >> 3;
    const int col0 = (blockIdx.x & 7) * 256;
    const int row0 = blockIdx.y * 256;
    const __bf16* __restrict__ Bp = segs.B[seg];

    // staging coords: 1024 chunks of 8 bf16 per 256x32 tile, 2 per thread
    const int sr0 = tid >> 2, sc = (tid & 3) * 8;   // i=0 row; i=1 row = sr0+128

    f32x4 acc[8][4] = {};

    // prologue: stage K-tile 0 into buffer 0
#pragma unroll
    for (int i = 0; i < 2; i++) {
        int r = sr0 + i * 128, idx = tid + i * 512;
        gload16(&A [(size_t)(row0 + r) * K + sc], &As[0][0][0] + idx * 8);
        gload16(&Bp[(size_t)(col0 + r) * K + sc], &Bs[0][0][0] + idx * 8);
    }

    int buf = 0;
    for (int k0 = 0; k0 < K; k0 += 32) {
        __syncthreads();    // implicit vmcnt(0): tile k0 resident in As/Bs[buf]
        if (k0 + 32 < K) {  // issue next tile; lands by the next barrier
#pragma unroll
            for (int i = 0; i < 2; i++) {
                int r = sr0 + i * 128, idx = tid + i * 512;
                gload16(&A [(size_t)(row0 + r) * K + k0 + 32 + sc],
                        &As[buf ^ 1][0][0] + idx * 8);
                gload16(&Bp[(size_t)(col0 + r) * K + k0 + 32 + sc],
                        &Bs[buf ^ 1][0][0] + idx * 8);
            }
        }
        bf16x8 af[8], bfr[4];
#pragma unroll
        for (int mt = 0; mt < 8; mt++)
            af[mt] = *reinterpret_cast<const bf16x8*>(&As[buf][wm + mt * 16 + lr][lq * 8]);
#pragma unroll
        for (int nt = 0; nt < 4; nt++)
            bfr[nt] = *reinterpret_cast<const bf16x8*>(&Bs[buf][wn + nt * 16 + lr][lq * 8]);
        __builtin_amdgcn_s_setprio(1);
#pragma unroll
        for (int mt = 0; mt < 8; mt++)
#pragma unroll
            for (int nt = 0; nt < 4; nt++)
                acc[mt][nt] = __builtin_amdgcn_mfma_f32_16x16x32_bf16(af[mt], bfr[nt],
                                                                      acc[mt][nt], 0, 0, 0);
        __builtin_amdgcn_s_setprio(0);
        buf ^= 1;
    }
    const float* bias = segs.bias[seg];
    const float alpha = segs.alpha[seg];
    const int op = segs.op[seg];
    void* Cv = segs.C[seg];

    if (op == 2) {
        // direct transpose: vT[d][s], 4 consecutive rows per lane (8B store)
#pragma unroll
        for (int mt = 0; mt < 8; mt++)
#pragma unroll
            for (int nt = 0; nt < 4; nt++) {
                int col = col0 + wn + nt * 16 + lr;
                float bv = bias[col];
                int rowb = row0 + wm + mt * 16 + lq * 4;
                bf16x4 o4;
#pragma unroll
                for (int r = 0; r < 4; r++) o4[r] = (__bf16)(acc[mt][nt][r] + bv);
                *reinterpret_cast<bf16x4*>(&((__bf16*)Cv)[(size_t)col * S + rowb]) = o4;
            }
    } else if (op == 1) {
        // rope epilogue: pair partner value lives in lane lr^1
#pragma unroll
        for (int mt = 0; mt < 8; mt++)
#pragma unroll
            for (int nt = 0; nt < 4; nt++) {
                int col = col0 + wn + nt * 16 + lr;
                float bv = bias[col];
                int i = (col & 127) >> 1;
                int odd = lr & 1;
#pragma unroll
                for (int r = 0; r < 4; r++) {
                    int row = row0 + wm + mt * 16 + lq * 4 + r;
                    float v = alpha * (acc[mt][nt][r] + bv);
                    float p = __shfl_xor(v, 1, 64);
                    float c = fcos[row * 64 + i];
                    float sn = fsin[row * 64 + i];
                    float out = odd ? (p * sn + v * c) : (v * c - p * sn);
                    ((__bf16*)Cv)[(size_t)row * D + col] = (__bf16)out;
                }
            }
    } else {
#pragma unroll
        for (int mt = 0; mt < 8; mt++)
#pragma unroll
            for (int nt = 0; nt < 4; nt++) {
                int col = col0 + wn + nt * 16 + lr;
                float bv = bias[col];
#pragma unroll
                for (int r = 0; r < 4; r++) {
                    int row = row0 + wm + mt * 16 + lq * 4 + r;
                    ((__bf16*)Cv)[(size_t)row * D + col] = (__bf16)(alpha * (acc[mt][nt][r] + bv));
                }
            }
    }
}

// ---------------- P GEMM: split-K x4, 128x128 tile, f32 partials ------------
// seg = K-quarter. 1024 blocks (4/CU) instead of 256 (1/CU): fixes the
// parallelism starvation of the final GEMM. No atomics: 4 disjoint partial
// buffers, summed (+bias) by reduceP_kn.
__global__ __launch_bounds__(256) void gemmP_kn(const __bf16* __restrict__ A,
                                                const __bf16* __restrict__ B,
                                                float* __restrict__ part) {
    __shared__ __bf16 As[2][128][32];
    __shared__ __bf16 Bs[2][128][32];
    const int tid = threadIdx.x;
    const int wave = tid >> 6, lane = tid & 63;
    const int lr = lane & 15, lq = lane >> 4;
    const int wm = (wave >> 1) * 64, wn = (wave & 1) * 64;
    const int seg  = blockIdx.x >> 4;
    const int col0 = (blockIdx.x & 15) * 128;
    const int row0 = blockIdx.y * 128;
    const int koff = seg * 512;          // this block's K window: [koff, koff+512)

    const int sr0 = tid >> 2, sc = (tid & 3) * 8;

    f32x4 acc[4][4] = {};

#pragma unroll
    for (int i = 0; i < 2; i++) {
        int r = sr0 + i * 64, idx = tid + i * 256;
        gload16(&A[(size_t)(row0 + r) * D + koff + sc], &As[0][0][0] + idx * 8);
        gload16(&B[(size_t)(col0 + r) * D + koff + sc], &Bs[0][0][0] + idx * 8);
    }

    int buf = 0;
    for (int k0 = 0; k0 < 512; k0 += 32) {
        __syncthreads();
        if (k0 + 32 < 512) {
#pragma unroll
            for (int i = 0; i < 2; i++) {
                int r = sr0 + i * 64, idx = tid + i * 256;
                gload16(&A[(size_t)(row0 + r) * D + koff + k0 + 32 + sc],
                        &As[buf ^ 1][0][0] + idx * 8);
                gload16(&B[(size_t)(col0 + r) * D + koff + k0 + 32 + sc],
                        &Bs[buf ^ 1][0][0] + idx * 8);
            }
        }
        bf16x8 af[4], bfr[4];
#pragma unroll
        for (int mt = 0; mt < 4; mt++)
            af[mt] = *reinterpret_cast<const bf16x8*>(&As[buf][wm + mt * 16 + lr][lq * 8]);
#pragma unroll
        for (int nt = 0; nt < 4; nt++)
            bfr[nt] = *reinterpret_cast<const bf16x8*>(&Bs[buf][wn + nt * 16 + lr][lq * 8]);
        __builtin_amdgcn_s_setprio(1);
#pragma unroll
        for (int mt = 0; mt < 4; mt++)
#pragma unroll
            for (int nt = 0; nt < 4; nt++)
                acc[mt][nt] = __builtin_amdgcn_mfma_f32_16x16x32_bf16(af[mt], bfr[nt],
                                                                      acc[mt][nt], 0, 0, 0);
        __builtin_amdgcn_s_setprio(0);
        buf ^= 1;
    }
    float* outp = part + (size_t)seg * S * D;
#pragma unroll
    for (int mt = 0; mt < 4; mt++)
#pragma unroll
        for (int nt = 0; nt < 4; nt++) {
            int col = col0 + wn + nt * 16 + lr;
#pragma unroll
            for (int r = 0; r < 4; r++) {
                int row = row0 + wm + mt * 16 + lq * 4 + r;
                outp[(size_t)row * D + col] = acc[mt][nt][r];
            }
        }
}

// sum 4 partials + bias -> f32 out
__global__ void reduceP_kn(const float* __restrict__ part,
                           const float* __restrict__ bias,
                           float* __restrict__ out) {
    const size_t n4 = (size_t)S * D / 4;
    size_t i = (size_t)blockIdx.x * 256 + threadIdx.x;   // < n4
    f32x4 a = reinterpret_cast<const f32x4*>(part)[i];
    f32x4 b = reinterpret_cast<const f32x4*>(part)[i + n4];
    f32x4 c = reinterpret_cast<const f32x4*>(part)[i + 2 * n4];
    f32x4 d = reinterpret_cast<const f32x4*>(part)[i + 3 * n4];
    f32x4 bv = reinterpret_cast<const f32x4*>(bias)[i & (D / 4 - 1)];
    reinterpret_cast<f32x4*>(out)[i] = (a + b) + (c + d) + bv;
}

// ---------------- fused attention (pipelined) -------------------------------
#define ATTN_STEP(T0, BUF, MC, MN)                                            \
  {                                                                           \
    __syncthreads(); /* drains vmcnt: K(i),V(i),mask(i) landed; waves sync */ \
    const int tnext = (T0) + 64;                                              \
    if (tnext < S) {                                                          \
      /* prefetch V(i+1) into the other buffer (covered by full iter) */      \
      _Pragma("unroll")                                                       \
      for (int i = 0; i < 4; i++) {                                           \
        int idx = tid + i * 256;                                              \
        int kc2 = idx >> 9, rv = (idx >> 2) & 127, cv = (idx & 3) * 8;        \
        gload16(&vT[(size_t)(h * HD + rv) * S + tnext + kc2 * 32 + cv],       \
                &Vs[(BUF) ^ 1][0][0][0] + idx * 8);                           \
      }                                                                       \
      /* prefetch mask(i+1) straight into registers (U2 A-fragment layout) */ \
      const float* mrow =                                                     \
          &mask[((size_t)h * S + qr0 + lr) * S + tnext + lq * 8];             \
      MN[0] = *reinterpret_cast<const float4*>(&mrow[0]);                     \
      MN[1] = *reinterpret_cast<const float4*>(&mrow[4]);                     \
      MN[2] = *reinterpret_cast<const float4*>(&mrow[32]);                    \
      MN[3] = *reinterpret_cast<const float4*>(&mrow[36]);                    \
    }                                                                         \
    /* ---- S phase: S = QK^T over current K tile ---- */                     \
    __builtin_amdgcn_s_setprio(1);                                            \
    _Pragma("unroll")                                                         \
    for (int ts = 0; ts < 4; ts++) {                                          \
      f32x4 c = {0.f, 0.f, 0.f, 0.f};                                         \
      _Pragma("unroll")                                                       \
      for (int kc = 0; kc < 4; kc++) {                                        \
        bf16x8 kf =                                                           \
            *reinterpret_cast<const bf16x8*>(&Ks[kc][ts * 16 + lr][lq * 8]);  \
        c = __builtin_amdgcn_mfma_f32_16x16x32_bf16(qf[kc], kf, c, 0, 0, 0);  \
      }                                                                       \
      _Pragma("unroll")                                                       \
      for (int r2 = 0; r2 < 4; r2++) {                                        \
        absacc[r2] += fabsf(c[r2]);                                           \
        Ps[wave][lq * 4 + r2][ts * 16 + lr] = (__bf16)c[r2];                  \
      }                                                                       \
    }                                                                         \
    __builtin_amdgcn_s_setprio(0);                                            \
    __builtin_amdgcn_s_barrier(); /* raw: all waves done reading Ks */        \
    if (tnext < S) {                                                          \
      /* refill K for next iter; latency covered by PV phase below */         \
      _Pragma("unroll")                                                       \
      for (int i = 0; i < 4; i++) {                                           \
        int idx = tid + i * 256;                                              \
        int rk = (idx >> 2) & 63, ck = (idx & 3) * 8;                         \
        gload16(&k[(size_t)(tnext + rk) * D + h * HD + i * 32 + ck],          \
                &Ks[0][0][0] + idx * 8);                                      \
      }                                                                       \
    }                                                                         \
    /* ---- PV phase: each vf feeds BOTH U2 (mask regs) and U (Ps) ---- */    \
    __builtin_amdgcn_s_setprio(1);                                            \
    _Pragma("unroll")                                                         \
    for (int kc2 = 0; kc2 < 2; kc2++) {                                       \
      bf16x8 pfm;                                                             \
      pfm[0] = (__bf16)MC[kc2 * 2].x;     pfm[1] = (__bf16)MC[kc2 * 2].y;     \
      pfm[2] = (__bf16)MC[kc2 * 2].z;     pfm[3] = (__bf16)MC[kc2 * 2].w;     \
      pfm[4] = (__bf16)MC[kc2 * 2 + 1].x; pfm[5] = (__bf16)MC[kc2 * 2 + 1].y; \
      pfm[6] = (__bf16)MC[kc2 * 2 + 1].z; pfm[7] = (__bf16)MC[kc2 * 2 + 1].w; \
      bf16x8 pfs =                                                            \
          *reinterpret_cast<const bf16x8*>(&Ps[wave][lr][kc2 * 32 + lq * 8]); \
      _Pragma("unroll")                                                       \
      for (int nt = 0; nt < 8; nt++) {                                        \
        bf16x8 vf = *reinterpret_cast<const bf16x8*>(                         \
            &Vs[BUF][kc2][nt * 16 + lr][lq * 8]);                             \
        U2[nt] = __builtin_amdgcn_mfma_f32_16x16x32_bf16(pfm, vf, U2[nt], 0, 0, 0); \
        U[nt]  = __builtin_amdgcn_mfma_f32_16x16x32_bf16(pfs, vf, U[nt], 0, 0, 0);  \
      }                                                                       \
    }                                                                         \
    __builtin_amdgcn_s_setprio(0);                                            \
  }

__global__ __launch_bounds__(256) void attn_kn(const __bf16* __restrict__ q,
                                               const __bf16* __restrict__ k,
                                               const __bf16* __restrict__ vT,
                                               const float* __restrict__ mask,
                                               const __bf16* __restrict__ g,
                                               const float* __restrict__ norm_w,
                                               __bf16* __restrict__ attn) {
    __shared__ __bf16 Ks[4][64][32];       // K tile (single-buffered)
    __shared__ __bf16 Vs[2][2][128][32];   // V tile, double-buffered
    __shared__ __bf16 Ps[4][16][72];       // per-wave P tile (16 q-rows x 64 t)

    // XCD-grouping swizzle: 512 blocks, 64 per XCD -> each XCD covers 2 heads
    const int bid = blockIdx.x + (blockIdx.y << 5);
    const int slot = bid >> 3;
    const int h = ((bid & 7) << 1) | (slot >> 5);
    const int qt = slot & 31;

    const int tid = threadIdx.x, wave = tid >> 6, lane = tid & 63;
    const int lr = lane & 15, lq = lane >> 4;
    const int qr0 = qt * 64 + wave * 16;

    bf16x8 qf[4];
#pragma unroll
    for (int kc = 0; kc < 4; kc++)
        qf[kc] = *reinterpret_cast<const bf16x8*>(
            &q[(size_t)(qr0 + lr) * D + h * HD + kc * 32 + lq * 8]);

    float absacc[4] = {0.f, 0.f, 0.f, 0.f};
    f32x4 U[8] = {};
    f32x4 U2[8] = {};
    float4 m_a[4], m_b[4];

    // ---- prologue: stage K(0), V(0)->Vs[0], mask(0)->m_a ----
#pragma unroll
    for (int i = 0; i < 4; i++) {
        int idx = tid + i * 256;
        int rk = (idx >> 2) & 63, ck = (idx & 3) * 8;
        gload16(&k[(size_t)rk * D + h * HD + i * 32 + ck], &Ks[0][0][0] + idx * 8);
    }
#pragma unroll
    for (int i = 0; i < 4; i++) {
        int idx = tid + i * 256;
        int kc2 = idx >> 9, rv = (idx >> 2) & 127, cv = (idx & 3) * 8;
        gload16(&vT[(size_t)(h * HD + rv) * S + kc2 * 32 + cv],
                &Vs[0][0][0][0] + idx * 8);
    }
    {
        const float* mrow = &mask[((size_t)h * S + qr0 + lr) * S + lq * 8];
        m_a[0] = *reinterpret_cast<const float4*>(&mrow[0]);
        m_a[1] = *reinterpret_cast<const float4*>(&mrow[4]);
        m_a[2] = *reinterpret_cast<const float4*>(&mrow[32]);
        m_a[3] = *reinterpret_cast<const float4*>(&mrow[36]);
    }

    for (int t0 = 0; t0 < S; t0 += 128) {
        ATTN_STEP(t0,      0, m_a, m_b)
        ATTN_STEP(t0 + 64, 1, m_b, m_a)
    }

    // rd = 1/clip(sum_t |S|)
    float rd[4];
#pragma unroll
    for (int r2 = 0; r2 < 4; r2++) {
        float v = absacc[r2];
#pragma unroll
        for (int off = 1; off < 16; off <<= 1) v += __shfl_xor(v, off, 64);
        rd[r2] = 1.0f / fminf(fmaxf(v, 1.0f), 50000.0f);
    }

    // O = rd*U + U2, RMS over hd, * norm_w * g
    float otot[8][4];
    float ssum[4] = {0.f, 0.f, 0.f, 0.f};
#pragma unroll
    for (int nt = 0; nt < 8; nt++)
#pragma unroll
        for (int r2 = 0; r2 < 4; r2++) {
            float v = U[nt][r2] * rd[r2] + U2[nt][r2];
            otot[nt][r2] = v;
            ssum[r2] += v * v;
        }
#pragma unroll
    for (int r2 = 0; r2 < 4; r2++) {
#pragma unroll
        for (int off = 1; off < 16; off <<= 1) ssum[r2] += __shfl_xor(ssum[r2], off, 64);
    }
    float rinv[4];
#pragma unroll
    for (int r2 = 0; r2 < 4; r2++) rinv[r2] = rsqrtf(ssum[r2] * (1.0f / HD) + 1e-5f);
#pragma unroll
    for (int nt = 0; nt < 8; nt++) {
        int col = nt * 16 + lr;
        float nw = norm_w[col];
#pragma unroll
        for (int r2 = 0; r2 < 4; r2++) {
            int row = qr0 + lq * 4 + r2;
            float val = otot[nt][r2] * rinv[r2] * nw * (float)g[(size_t)row * D + h * HD + col];
            attn[(size_t)row * D + h * HD + col] = (__bf16)val;
        }
    }
}

extern "C" void kernel_launch(void* const* d_in, const int* in_sizes, int n_in,
                              void* d_out, int out_size, void* d_ws, size_t ws_size,
                              hipStream_t stream) {
    const float* x    = (const float*)d_in[0];
    const float* fcos = (const float*)d_in[1];
    const float* fsin = (const float*)d_in[2];
    const float* mask = (const float*)d_in[3];
    const float* Wq   = (const float*)d_in[4];
    const float* bq   = (const float*)d_in[5];
    const float* Wk   = (const float*)d_in[6];
    const float* bk   = (const float*)d_in[7];
    const float* Wv   = (const float*)d_in[8];
    const float* bv   = (const float*)d_in[9];
    const float* Wg   = (const float*)d_in[10];
    const float* bg   = (const float*)d_in[11];
    const float* Wp   = (const float*)d_in[12];
    const float* bp   = (const float*)d_in[13];
    const float* normw= (const float*)d_in[14];

    char* w = (char*)d_ws;
    auto alloc = [&](size_t b) { void* p = (void*)w; w += (b + 255) & ~(size_t)255; return p; };
    const size_t SD = (size_t)S * D;

    __bf16* xb  = (__bf16*)alloc(SD * 2);
    __bf16* wqb = (__bf16*)alloc(SD * 2);
    __bf16* wkb = (__bf16*)alloc(SD * 2);
    __bf16* wvb = (__bf16*)alloc(SD * 2);
    __bf16* wgb = (__bf16*)alloc(SD * 2);
    __bf16* wpb = (__bf16*)alloc(SD * 2);
    __bf16* qb  = (__bf16*)alloc(SD * 2);
    __bf16* kb  = (__bf16*)alloc(SD * 2);
    __bf16* vTb = (__bf16*)alloc(SD * 2);
    __bf16* gb  = (__bf16*)alloc(SD * 2);
    float*  part= (float*) alloc(SD * 4 * 4);   // 4 split-K partials, f32
    __bf16* atb = xb;   // alias: xb dead after QKVG gemm

    CvtArgs ca;
    ca.src[0] = x;  ca.dst[0] = xb;
    ca.src[1] = Wq; ca.dst[1] = wqb;
    ca.src[2] = Wk; ca.dst[2] = wkb;
    ca.src[3] = Wv; ca.dst[3] = wvb;
    ca.src[4] = Wg; ca.dst[4] = wgb;
    ca.src[5] = Wp; ca.dst[5] = wpb;
    cvt_kn<<<6 * 4096, 256, 0, stream>>>(ca);

    const float scaling = 0.08838834764831845f;  // 128^-0.5
    SegArgs qkvg;
    qkvg.B[0] = wqb; qkvg.B[1] = wkb; qkvg.B[2] = wvb; qkvg.B[3] = wgb;
    qkvg.bias[0] = bq; qkvg.bias[1] = bk; qkvg.bias[2] = bv; qkvg.bias[3] = bg;
    qkvg.C[0] = qb; qkvg.C[1] = kb; qkvg.C[2] = vTb; qkvg.C[3] = gb;
    qkvg.alpha[0] = 1.0f; qkvg.alpha[1] = scaling; qkvg.alpha[2] = 1.0f; qkvg.alpha[3] = 1.0f;
    qkvg.op[0] = 1; qkvg.op[1] = 1; qkvg.op[2] = 2; qkvg.op[3] = 0;
    gemm256_kn<<<dim3(32, 8), 512, 0, stream>>>(xb, qkvg, fcos, fsin, D);

    attn_kn<<<dim3(32, 16), 256, 0, stream>>>(qb, kb, vTb, mask, gb, normw, atb);

    gemmP_kn<<<dim3(64, 16), 256, 0, stream>>>(atb, wpb, part);
    reduceP_kn<<<SD / 4 / 256, 256, 0, stream>>>(part, bp, (float*)d_out);
}

// Round 5
// 616.426 us; speedup vs baseline: 1.1514x; 1.0336x over previous
//
#include <hip/hip_runtime.h>
#include <hip/hip_bf16.h>
#include <stdint.h>

#define S 2048
#define D 2048
#define H 16
#define HD 128

typedef __bf16 bf16x8 __attribute__((ext_vector_type(8)));
typedef __bf16 bf16x4 __attribute__((ext_vector_type(4)));
typedef float f32x4 __attribute__((ext_vector_type(4)));

// async global->LDS DMA, 16B per lane; LDS dest = wave-uniform base + lane*16
__device__ __forceinline__ void gload16(const void* g, void* l) {
    __builtin_amdgcn_global_load_lds(
        (const __attribute__((address_space(1))) unsigned int*)g,
        (__attribute__((address_space(3))) unsigned int*)l, 16, 0, 0);
}

// ---------------- merged f32 -> bf16 convert (6 arrays, exact grid) ---------
struct CvtArgs { const float* src[6]; __bf16* dst[6]; };

__global__ void cvt_kn(CvtArgs a) {
    int which = blockIdx.x >> 12;                    // 4096 blocks per array
    int i = (blockIdx.x & 4095) * 256 + threadIdx.x; // < SD/4
    float4 v = reinterpret_cast<const float4*>(a.src[which])[i];
    bf16x4 o = { (__bf16)v.x, (__bf16)v.y, (__bf16)v.z, (__bf16)v.w };
    reinterpret_cast<bf16x4*>(a.dst[which])[i] = o;
}

// ---------------- QKVG GEMM: 256x256 tile, BK=64, 2-phase prefetch ----------
// 512 threads = 8 waves (2 M-waves x 4 N-waves), per-wave 128x64 output.
// BK=64: 64 MFMA/wave per barrier interval (~600 cyc issue x 2 waves/SIMD)
// >> global->LDS latency, and half the barrier/drain count of BK=32.
// LDS = 128 KB (1 block/CU; grid is exactly 1/CU anyway).
struct SegArgs {
    const __bf16* B[4];
    const float*  bias[4];
    void*         C[4];
    float         alpha[4];
    int           op[4];
};

__global__ __launch_bounds__(512) void gemm256_kn(const __bf16* __restrict__ A,
                                                  SegArgs segs,
                                                  const float* __restrict__ fcos,
                                                  const float* __restrict__ fsin,
                                                  int K) {
    __shared__ __bf16 As[2][256][64];   // 64 KB  (unpadded: global_load_lds)
    __shared__ __bf16 Bs[2][256][64];   // 64 KB
    const int tid = threadIdx.x;
    const int wave = tid >> 6, lane = tid & 63;
    const int lr = lane & 15, lq = lane >> 4;
    const int wm = (wave >> 2) * 128, wn = (wave & 3) * 64;
    const int seg  = blockIdx.x >> 3;
    const int col0 = (blockIdx.x & 7) * 256;
    const int row0 = blockIdx.y * 256;
    const __bf16* __restrict__ Bp = segs.B[seg];

    // staging coords: 2048 chunks of 8 bf16 per 256x64 tile, 4 per thread
    // chunk idx -> row = idx>>3, col = (idx&7)*8 ; LDS dest linear = idx*16B
    const int sr = tid >> 3, sc = (tid & 7) * 8;    // i-th chunk row = sr + i*64

    f32x4 acc[8][4] = {};

    // prologue: stage K-tile 0 into buffer 0
#pragma unroll
    for (int i = 0; i < 4; i++) {
        int r = sr + i * 64, idx = tid + i * 512;
        gload16(&A [(size_t)(row0 + r) * K + sc], &As[0][0][0] + idx * 8);
        gload16(&Bp[(size_t)(col0 + r) * K + sc], &Bs[0][0][0] + idx * 8);
    }

    int buf = 0;
    for (int k0 = 0; k0 < K; k0 += 64) {
        __syncthreads();    // implicit vmcnt(0): tile k0 resident in As/Bs[buf]
        if (k0 + 64 < K) {  // issue next tile; full interval to land
#pragma unroll
            for (int i = 0; i < 4; i++) {
                int r = sr + i * 64, idx = tid + i * 512;
                gload16(&A [(size_t)(row0 + r) * K + k0 + 64 + sc],
                        &As[buf ^ 1][0][0] + idx * 8);
                gload16(&Bp[(size_t)(col0 + r) * K + k0 + 64 + sc],
                        &Bs[buf ^ 1][0][0] + idx * 8);
            }
        }
#pragma unroll
        for (int kk = 0; kk < 2; kk++) {
            bf16x8 af[8], bfr[4];
#pragma unroll
            for (int mt = 0; mt < 8; mt++)
                af[mt] = *reinterpret_cast<const bf16x8*>(
                    &As[buf][wm + mt * 16 + lr][kk * 32 + lq * 8]);
#pragma unroll
            for (int nt = 0; nt < 4; nt++)
                bfr[nt] = *reinterpret_cast<const bf16x8*>(
                    &Bs[buf][wn + nt * 16 + lr][kk * 32 + lq * 8]);
            __builtin_amdgcn_s_setprio(1);
#pragma unroll
            for (int mt = 0; mt < 8; mt++)
#pragma unroll
                for (int nt = 0; nt < 4; nt++)
                    acc[mt][nt] = __builtin_amdgcn_mfma_f32_16x16x32_bf16(
                        af[mt], bfr[nt], acc[mt][nt], 0, 0, 0);
            __builtin_amdgcn_s_setprio(0);
        }
        buf ^= 1;
    }
    const float* bias = segs.bias[seg];
    const float alpha = segs.alpha[seg];
    const int op = segs.op[seg];
    void* Cv = segs.C[seg];

    if (op == 2) {
        // direct transpose: vT[d][s], 4 consecutive rows per lane (8B store)
#pragma unroll
        for (int mt = 0; mt < 8; mt++)
#pragma unroll
            for (int nt = 0; nt < 4; nt++) {
                int col = col0 + wn + nt * 16 + lr;
                float bv = bias[col];
                int rowb = row0 + wm + mt * 16 + lq * 4;
                bf16x4 o4;
#pragma unroll
                for (int r = 0; r < 4; r++) o4[r] = (__bf16)(acc[mt][nt][r] + bv);
                *reinterpret_cast<bf16x4*>(&((__bf16*)Cv)[(size_t)col * S + rowb]) = o4;
            }
    } else if (op == 1) {
        // rope epilogue: pair partner value lives in lane lr^1
#pragma unroll
        for (int mt = 0; mt < 8; mt++)
#pragma unroll
            for (int nt = 0; nt < 4; nt++) {
                int col = col0 + wn + nt * 16 + lr;
                float bv = bias[col];
                int i = (col & 127) >> 1;
                int odd = lr & 1;
#pragma unroll
                for (int r = 0; r < 4; r++) {
                    int row = row0 + wm + mt * 16 + lq * 4 + r;
                    float v = alpha * (acc[mt][nt][r] + bv);
                    float p = __shfl_xor(v, 1, 64);
                    float c = fcos[row * 64 + i];
                    float sn = fsin[row * 64 + i];
                    float out = odd ? (p * sn + v * c) : (v * c - p * sn);
                    ((__bf16*)Cv)[(size_t)row * D + col] = (__bf16)out;
                }
            }
    } else {
#pragma unroll
        for (int mt = 0; mt < 8; mt++)
#pragma unroll
            for (int nt = 0; nt < 4; nt++) {
                int col = col0 + wn + nt * 16 + lr;
                float bv = bias[col];
#pragma unroll
                for (int r = 0; r < 4; r++) {
                    int row = row0 + wm + mt * 16 + lq * 4 + r;
                    ((__bf16*)Cv)[(size_t)row * D + col] = (__bf16)(alpha * (acc[mt][nt][r] + bv));
                }
            }
    }
}

// ---------------- P GEMM: split-K x4, 128x128 tile, f32 partials ------------
__global__ __launch_bounds__(256) void gemmP_kn(const __bf16* __restrict__ A,
                                                const __bf16* __restrict__ B,
                                                float* __restrict__ part) {
    __shared__ __bf16 As[2][128][32];
    __shared__ __bf16 Bs[2][128][32];
    const int tid = threadIdx.x;
    const int wave = tid >> 6, lane = tid & 63;
    const int lr = lane & 15, lq = lane >> 4;
    const int wm = (wave >> 1) * 64, wn = (wave & 1) * 64;
    const int seg  = blockIdx.x >> 4;
    const int col0 = (blockIdx.x & 15) * 128;
    const int row0 = blockIdx.y * 128;
    const int koff = seg * 512;          // this block's K window: [koff, koff+512)

    const int sr0 = tid >> 2, sc = (tid & 3) * 8;

    f32x4 acc[4][4] = {};

#pragma unroll
    for (int i = 0; i < 2; i++) {
        int r = sr0 + i * 64, idx = tid + i * 256;
        gload16(&A[(size_t)(row0 + r) * D + koff + sc], &As[0][0][0] + idx * 8);
        gload16(&B[(size_t)(col0 + r) * D + koff + sc], &Bs[0][0][0] + idx * 8);
    }

    int buf = 0;
    for (int k0 = 0; k0 < 512; k0 += 32) {
        __syncthreads();
        if (k0 + 32 < 512) {
#pragma unroll
            for (int i = 0; i < 2; i++) {
                int r = sr0 + i * 64, idx = tid + i * 256;
                gload16(&A[(size_t)(row0 + r) * D + koff + k0 + 32 + sc],
                        &As[buf ^ 1][0][0] + idx * 8);
                gload16(&B[(size_t)(col0 + r) * D + koff + k0 + 32 + sc],
                        &Bs[buf ^ 1][0][0] + idx * 8);
            }
        }
        bf16x8 af[4], bfr[4];
#pragma unroll
        for (int mt = 0; mt < 4; mt++)
            af[mt] = *reinterpret_cast<const bf16x8*>(&As[buf][wm + mt * 16 + lr][lq * 8]);
#pragma unroll
        for (int nt = 0; nt < 4; nt++)
            bfr[nt] = *reinterpret_cast<const bf16x8*>(&Bs[buf][wn + nt * 16 + lr][lq * 8]);
        __builtin_amdgcn_s_setprio(1);
#pragma unroll
        for (int mt = 0; mt < 4; mt++)
#pragma unroll
            for (int nt = 0; nt < 4; nt++)
                acc[mt][nt] = __builtin_amdgcn_mfma_f32_16x16x32_bf16(af[mt], bfr[nt],
                                                                      acc[mt][nt], 0, 0, 0);
        __builtin_amdgcn_s_setprio(0);
        buf ^= 1;
    }
    float* outp = part + (size_t)seg * S * D;
#pragma unroll
    for (int mt = 0; mt < 4; mt++)
#pragma unroll
        for (int nt = 0; nt < 4; nt++) {
            int col = col0 + wn + nt * 16 + lr;
#pragma unroll
            for (int r = 0; r < 4; r++) {
                int row = row0 + wm + mt * 16 + lq * 4 + r;
                outp[(size_t)row * D + col] = acc[mt][nt][r];
            }
        }
}

// sum 4 partials + bias -> f32 out
__global__ void reduceP_kn(const float* __restrict__ part,
                           const float* __restrict__ bias,
                           float* __restrict__ out) {
    const size_t n4 = (size_t)S * D / 4;
    size_t i = (size_t)blockIdx.x * 256 + threadIdx.x;   // < n4
    f32x4 a = reinterpret_cast<const f32x4*>(part)[i];
    f32x4 b = reinterpret_cast<const f32x4*>(part)[i + n4];
    f32x4 c = reinterpret_cast<const f32x4*>(part)[i + 2 * n4];
    f32x4 d = reinterpret_cast<const f32x4*>(part)[i + 3 * n4];
    f32x4 bv = reinterpret_cast<const f32x4*>(bias)[i & (D / 4 - 1)];
    reinterpret_cast<f32x4*>(out)[i] = (a + b) + (c + d) + bv;
}

// ---------------- fused attention (fully double-buffered) -------------------
// Per t-tile: S = QK^T ; absacc += |S| ; {U += S@V, U2 += mask@V} merged.
// K, V, AND mask are all prefetched one FULL iteration ahead (K/V double-
// buffered in LDS, mask in registers). ONE barrier per iteration; its
// implicit vmcnt(0) drain only waits on DMA that has had a whole iteration
// (~1000+ cyc) to fly. No mid-iteration barrier, no short-coverage K refill.
// Hazards: Ps is strictly per-wave (wave-internal lgkmcnt ordering);
// Ks/Vs[BUF^1] was last read in iter i-1, and all waves crossed the top
// barrier before the iter-i DMA into it issues.
#define ATTN_STEP(T0, BUF, MC, MN)                                            \
  {                                                                           \
    __syncthreads(); /* drains vmcnt: K(i),V(i),mask(i) landed; waves sync */ \
    const int tnext = (T0) + 64;                                              \
    if (tnext < S) {                                                          \
      /* prefetch K(i+1) into the other K buffer */                           \
      _Pragma("unroll")                                                       \
      for (int i = 0; i < 4; i++) {                                           \
        int idx = tid + i * 256;                                              \
        int rk = (idx >> 2) & 63, ck = (idx & 3) * 8;                         \
        gload16(&k[(size_t)(tnext + rk) * D + h * HD + i * 32 + ck],          \
                &Ks[(BUF) ^ 1][0][0][0] + idx * 8);                           \
      }                                                                       \
      /* prefetch V(i+1) into the other V buffer */                           \
      _Pragma("unroll")                                                       \
      for (int i = 0; i < 4; i++) {                                           \
        int idx = tid + i * 256;                                              \
        int kc2 = idx >> 9, rv = (idx >> 2) & 127, cv = (idx & 3) * 8;        \
        gload16(&vT[(size_t)(h * HD + rv) * S + tnext + kc2 * 32 + cv],       \
                &Vs[(BUF) ^ 1][0][0][0] + idx * 8);                           \
      }                                                                       \
      /* prefetch mask(i+1) straight into registers (U2 A-fragment layout) */ \
      const float* mrow =                                                     \
          &mask[((size_t)h * S + qr0 + lr) * S + tnext + lq * 8];             \
      MN[0] = *reinterpret_cast<const float4*>(&mrow[0]);                     \
      MN[1] = *reinterpret_cast<const float4*>(&mrow[4]);                     \
      MN[2] = *reinterpret_cast<const float4*>(&mrow[32]);                    \
      MN[3] = *reinterpret_cast<const float4*>(&mrow[36]);                    \
    }                                                                         \
    /* ---- S phase: S = QK^T over current K tile ---- */                     \
    __builtin_amdgcn_s_setprio(1);                                            \
    _Pragma("unroll")                                                         \
    for (int ts = 0; ts < 4; ts++) {                                          \
      f32x4 c = {0.f, 0.f, 0.f, 0.f};                                         \
      _Pragma("unroll")                                                       \
      for (int kc = 0; kc < 4; kc++) {                                        \
        bf16x8 kf = *reinterpret_cast<const bf16x8*>(                         \
            &Ks[BUF][kc][ts * 16 + lr][lq * 8]);                              \
        c = __builtin_amdgcn_mfma_f32_16x16x32_bf16(qf[kc], kf, c, 0, 0, 0);  \
      }                                                                       \
      _Pragma("unroll")                                                       \
      for (int r2 = 0; r2 < 4; r2++) {                                        \
        absacc[r2] += fabsf(c[r2]);                                           \
        Ps[wave][lq * 4 + r2][ts * 16 + lr] = (__bf16)c[r2];                  \
      }                                                                       \
    }                                                                         \
    /* ---- PV phase: each vf feeds BOTH U2 (mask regs) and U (Ps) ---- */    \
    _Pragma("unroll")                                                         \
    for (int kc2 = 0; kc2 < 2; kc2++) {                                       \
      bf16x8 pfm;                                                             \
      pfm[0] = (__bf16)MC[kc2 * 2].x;     pfm[1] = (__bf16)MC[kc2 * 2].y;     \
      pfm[2] = (__bf16)MC[kc2 * 2].z;     pfm[3] = (__bf16)MC[kc2 * 2].w;     \
      pfm[4] = (__bf16)MC[kc2 * 2 + 1].x; pfm[5] = (__bf16)MC[kc2 * 2 + 1].y; \
      pfm[6] = (__bf16)MC[kc2 * 2 + 1].z; pfm[7] = (__bf16)MC[kc2 * 2 + 1].w; \
      bf16x8 pfs =                                                            \
          *reinterpret_cast<const bf16x8*>(&Ps[wave][lr][kc2 * 32 + lq * 8]); \
      _Pragma("unroll")                                                       \
      for (int nt = 0; nt < 8; nt++) {                                        \
        bf16x8 vf = *reinterpret_cast<const bf16x8*>(                         \
            &Vs[BUF][kc2][nt * 16 + lr][lq * 8]);                             \
        U2[nt] = __builtin_amdgcn_mfma_f32_16x16x32_bf16(pfm, vf, U2[nt], 0, 0, 0); \
        U[nt]  = __builtin_amdgcn_mfma_f32_16x16x32_bf16(pfs, vf, U[nt], 0, 0, 0);  \
      }                                                                       \
    }                                                                         \
    __builtin_amdgcn_s_setprio(0);                                            \
  }

__global__ __launch_bounds__(256) void attn_kn(const __bf16* __restrict__ q,
                                               const __bf16* __restrict__ k,
                                               const __bf16* __restrict__ vT,
                                               const float* __restrict__ mask,
                                               const __bf16* __restrict__ g,
                                               const float* __restrict__ norm_w,
                                               __bf16* __restrict__ attn) {
    __shared__ __bf16 Ks[2][4][64][32];    // K tile, double-buffered (32 KB)
    __shared__ __bf16 Vs[2][2][128][32];   // V tile, double-buffered (32 KB)
    __shared__ __bf16 Ps[4][16][72];       // per-wave P tile (9.2 KB)

    // XCD-grouping swizzle: 512 blocks, 64 per XCD -> each XCD covers 2 heads
    const int bid = blockIdx.x + (blockIdx.y << 5);
    const int slot = bid >> 3;
    const int h = ((bid & 7) << 1) | (slot >> 5);
    const int qt = slot & 31;

    const int tid = threadIdx.x, wave = tid >> 6, lane = tid & 63;
    const int lr = lane & 15, lq = lane >> 4;
    const int qr0 = qt * 64 + wave * 16;

    bf16x8 qf[4];
#pragma unroll
    for (int kc = 0; kc < 4; kc++)
        qf[kc] = *reinterpret_cast<const bf16x8*>(
            &q[(size_t)(qr0 + lr) * D + h * HD + kc * 32 + lq * 8]);

    float absacc[4] = {0.f, 0.f, 0.f, 0.f};
    f32x4 U[8] = {};
    f32x4 U2[8] = {};
    float4 m_a[4], m_b[4];

    // ---- prologue: stage K(0)->Ks[0], V(0)->Vs[0], mask(0)->m_a ----
#pragma unroll
    for (int i = 0; i < 4; i++) {
        int idx = tid + i * 256;
        int rk = (idx >> 2) & 63, ck = (idx & 3) * 8;
        gload16(&k[(size_t)rk * D + h * HD + i * 32 + ck], &Ks[0][0][0][0] + idx * 8);
    }
#pragma unroll
    for (int i = 0; i < 4; i++) {
        int idx = tid + i * 256;
        int kc2 = idx >> 9, rv = (idx >> 2) & 127, cv = (idx & 3) * 8;
        gload16(&vT[(size_t)(h * HD + rv) * S + kc2 * 32 + cv],
                &Vs[0][0][0][0] + idx * 8);
    }
    {
        const float* mrow = &mask[((size_t)h * S + qr0 + lr) * S + lq * 8];
        m_a[0] = *reinterpret_cast<const float4*>(&mrow[0]);
        m_a[1] = *reinterpret_cast<const float4*>(&mrow[4]);
        m_a[2] = *reinterpret_cast<const float4*>(&mrow[32]);
        m_a[3] = *reinterpret_cast<const float4*>(&mrow[36]);
    }

    for (int t0 = 0; t0 < S; t0 += 128) {
        ATTN_STEP(t0,      0, m_a, m_b)
        ATTN_STEP(t0 + 64, 1, m_b, m_a)
    }

    // rd = 1/clip(sum_t |S|)
    float rd[4];
#pragma unroll
    for (int r2 = 0; r2 < 4; r2++) {
        float v = absacc[r2];
#pragma unroll
        for (int off = 1; off < 16; off <<= 1) v += __shfl_xor(v, off, 64);
        rd[r2] = 1.0f / fminf(fmaxf(v, 1.0f), 50000.0f);
    }

    // O = rd*U + U2, RMS over hd, * norm_w * g
    float otot[8][4];
    float ssum[4] = {0.f, 0.f, 0.f, 0.f};
#pragma unroll
    for (int nt = 0; nt < 8; nt++)
#pragma unroll
        for (int r2 = 0; r2 < 4; r2++) {
            float v = U[nt][r2] * rd[r2] + U2[nt][r2];
            otot[nt][r2] = v;
            ssum[r2] += v * v;
        }
#pragma unroll
    for (int r2 = 0; r2 < 4; r2++) {
#pragma unroll
        for (int off = 1; off < 16; off <<= 1) ssum[r2] += __shfl_xor(ssum[r2], off, 64);
    }
    float rinv[4];
#pragma unroll
    for (int r2 = 0; r2 < 4; r2++) rinv[r2] = rsqrtf(ssum[r2] * (1.0f / HD) + 1e-5f);
#pragma unroll
    for (int nt = 0; nt < 8; nt++) {
        int col = nt * 16 + lr;
        float nw = norm_w[col];
#pragma unroll
        for (int r2 = 0; r2 < 4; r2++) {
            int row = qr0 + lq * 4 + r2;
            float val = otot[nt][r2] * rinv[r2] * nw * (float)g[(size_t)row * D + h * HD + col];
            attn[(size_t)row * D + h * HD + col] = (__bf16)val;
        }
    }
}

extern "C" void kernel_launch(void* const* d_in, const int* in_sizes, int n_in,
                              void* d_out, int out_size, void* d_ws, size_t ws_size,
                              hipStream_t stream) {
    const float* x    = (const float*)d_in[0];
    const float* fcos = (const float*)d_in[1];
    const float* fsin = (const float*)d_in[2];
    const float* mask = (const float*)d_in[3];
    const float* Wq   = (const float*)d_in[4];
    const float* bq   = (const float*)d_in[5];
    const float* Wk   = (const float*)d_in[6];
    const float* bk   = (const float*)d_in[7];
    const float* Wv   = (const float*)d_in[8];
    const float* bv   = (const float*)d_in[9];
    const float* Wg   = (const float*)d_in[10];
    const float* bg   = (const float*)d_in[11];
    const float* Wp   = (const float*)d_in[12];
    const float* bp   = (const float*)d_in[13];
    const float* normw= (const float*)d_in[14];

    char* w = (char*)d_ws;
    auto alloc = [&](size_t b) { void* p = (void*)w; w += (b + 255) & ~(size_t)255; return p; };
    const size_t SD = (size_t)S * D;

    __bf16* xb  = (__bf16*)alloc(SD * 2);
    __bf16* wqb = (__bf16*)alloc(SD * 2);
    __bf16* wkb = (__bf16*)alloc(SD * 2);
    __bf16* wvb = (__bf16*)alloc(SD * 2);
    __bf16* wgb = (__bf16*)alloc(SD * 2);
    __bf16* wpb = (__bf16*)alloc(SD * 2);
    __bf16* qb  = (__bf16*)alloc(SD * 2);
    __bf16* kb  = (__bf16*)alloc(SD * 2);
    __bf16* vTb = (__bf16*)alloc(SD * 2);
    __bf16* gb  = (__bf16*)alloc(SD * 2);
    float*  part= (float*) alloc(SD * 4 * 4);   // 4 split-K partials, f32
    __bf16* atb = xb;   // alias: xb dead after QKVG gemm

    CvtArgs ca;
    ca.src[0] = x;  ca.dst[0] = xb;
    ca.src[1] = Wq; ca.dst[1] = wqb;
    ca.src[2] = Wk; ca.dst[2] = wkb;
    ca.src[3] = Wv; ca.dst[3] = wvb;
    ca.src[4] = Wg; ca.dst[4] = wgb;
    ca.src[5] = Wp; ca.dst[5] = wpb;
    cvt_kn<<<6 * 4096, 256, 0, stream>>>(ca);

    const float scaling = 0.08838834764831845f;  // 128^-0.5
    SegArgs qkvg;
    qkvg.B[0] = wqb; qkvg.B[1] = wkb; qkvg.B[2] = wvb; qkvg.B[3] = wgb;
    qkvg.bias[0] = bq; qkvg.bias[1] = bk; qkvg.bias[2] = bv; qkvg.bias[3] = bg;
    qkvg.C[0] = qb; qkvg.C[1] = kb; qkvg.C[2] = vTb; qkvg.C[3] = gb;
    qkvg.alpha[0] = 1.0f; qkvg.alpha[1] = scaling; qkvg.alpha[2] = 1.0f; qkvg.alpha[3] = 1.0f;
    qkvg.op[0] = 1; qkvg.op[1] = 1; qkvg.op[2] = 2; qkvg.op[3] = 0;
    gemm256_kn<<<dim3(32, 8), 512, 0, stream>>>(xb, qkvg, fcos, fsin, D);

    attn_kn<<<dim3(32, 16), 256, 0, stream>>>(qb, kb, vTb, mask, gb, normw, atb);

    gemmP_kn<<<dim3(64, 16), 256, 0, stream>>>(atb, wpb, part);
    reduceP_kn<<<SD / 4 / 256, 256, 0, stream>>>(part, bp, (float*)d_out);
}